// Round 10
// baseline (115.100 us; speedup 1.0000x reference)
//
#include <hip/hip_runtime.h>

#define HH 1024
#define WW 1024
#define KK 9
#define PADK 4
#define BW 64      // pixels per job (one row segment)
#define TCOL 72    // BW + 2*PADK
#define NW 81
#define NJOB 32    // jobs per persistent wave; 512 blocks x 32 = 16384 jobs

#define GLDS(src, dst, w)                                              \
  __builtin_amdgcn_global_load_lds(                                    \
      (const __attribute__((address_space(1))) unsigned int*)(src),    \
      (__attribute__((address_space(3))) unsigned int*)(dst), w, 0, 0)

// Persistent-wave pipelined KPN. Block = 1 wave = 32 sequential 64-pixel jobs.
// Double-buffered LDS: weights (20736 B contiguous per job, staged via 21
// linear width-16/4 global_load_lds) + 9x72 float4 reflect tile. Counted
// s_waitcnt vmcnt(21) leaves the NEXT job's 21 DMA ops in flight across the
// current job's compute -> every wave keeps ~20.7 KB outstanding at all
// times (2 waves/CU x 20.7 KB >> ~10 KB BDP), no barriers, no vmcnt(0)
// convoy (rounds 2/5's failure modes).
__global__ __launch_bounds__(64) void denoiser_kpn(
    const float* __restrict__ unet, const float* __restrict__ cnn,
    float* __restrict__ out) {
  __shared__ __attribute__((aligned(16))) float wlds[2][BW * NW];  // 2x20736 B
  __shared__ float4 tile[2][KK * TCOL];                            // 2x10368 B

  const int lane = threadIdx.x;
  const int job0 = blockIdx.x * NJOB;

  float tr[11][3];  // staged tile entries (648 = 10*64 + 8), static-indexed

  auto tile_load = [&](int job) {
    const int py = job >> 4;
    const int px0 = (job & 15) * BW;
#pragma unroll
    for (int i = 0; i < 11; ++i) {
      int e = i * 64 + lane;
      if (i == 10 && lane >= 8) e = 647;  // dup load, write is predicated
      const int r = e / TCOL;
      const int c = e - r * TCOL;
      int gy = py - PADK + r;
      gy = gy < 0 ? -gy : (gy >= HH ? 2 * HH - 2 - gy : gy);
      int gx = px0 - PADK + c;
      gx = gx < 0 ? -gx : (gx >= WW ? 2 * WW - 2 - gx : gx);
      __builtin_memcpy(&tr[i][0], unet + ((size_t)gy * WW + gx) * 3, 12);
    }
  };

  auto tile_write = [&](int buf) {
#pragma unroll
    for (int i = 0; i < 10; ++i)
      tile[buf][i * 64 + lane] = make_float4(tr[i][0], tr[i][1], tr[i][2], 0.f);
    if (lane < 8)
      tile[buf][640 + lane] = make_float4(tr[10][0], tr[10][1], tr[10][2], 0.f);
  };

  auto wdma = [&](int job, int buf) {  // exactly 21 VMEM ops, fully linear
    const char* s =
        (const char*)(cnn + ((size_t)(job >> 4) * WW + (job & 15) * BW) * NW);
    char* d = (char*)&wlds[buf][0];
#pragma unroll
    for (int i = 0; i < 20; ++i)
      GLDS(s + i * 1024 + lane * 16, d + i * 1024 + lane * 16, 16);
    GLDS(s + 20480 + lane * 4, d + 20480 + lane * 4, 4);
  };

  auto run = [&](int job, int buf) {
    float ax = 0.f, ay = 0.f, az = 0.f;
    const float* wrow = &wlds[buf][lane * NW];
#pragma unroll
    for (int ki = 0; ki < KK; ++ki)
#pragma unroll
      for (int kj = 0; kj < KK; ++kj) {
        const float4 pv = tile[buf][ki * TCOL + lane + kj];
        const float w = wrow[ki * KK + kj];
        ax = fmaf(w, pv.x, ax);
        ay = fmaf(w, pv.y, ay);
        az = fmaf(w, pv.z, az);
      }
    const int py = job >> 4;
    const int px = (job & 15) * BW + lane;
    const float o[3] = {ax, ay, az};
    __builtin_memcpy(out + ((size_t)py * WW + px) * 3, &o[0], 12);
  };

  // Prologue: prep job 0 into buffer 0 (DMA(0) left in flight).
  tile_load(job0);
  __builtin_amdgcn_sched_barrier(0);
  wdma(job0, 0);
  __builtin_amdgcn_sched_barrier(0);
  tile_write(0);  // compiler-inserted wait covers tr deps, leaves DMA(0) out

#pragma unroll 1
  for (int t = 0; t < NJOB; ++t) {
    const int cur = t & 1;
    if (t + 1 < NJOB) {
      tile_load(job0 + t + 1);
      __builtin_amdgcn_sched_barrier(0);
      wdma(job0 + t + 1, cur ^ 1);
      __builtin_amdgcn_sched_barrier(0);
      // Drain DMA(t) + tile loads(t+1); keep DMA(t+1) (newest 21) in flight.
      asm volatile("s_waitcnt vmcnt(21)" ::: "memory");
      __builtin_amdgcn_sched_barrier(0);
      tile_write(cur ^ 1);
    } else {
      asm volatile("s_waitcnt vmcnt(0)" ::: "memory");
      __builtin_amdgcn_sched_barrier(0);
    }
    run(job0 + t, cur);
  }
}

extern "C" void kernel_launch(void* const* d_in, const int* in_sizes, int n_in,
                              void* d_out, int out_size, void* d_ws, size_t ws_size,
                              hipStream_t stream) {
  const float* unet = (const float*)d_in[0];  // [1024,1024,3] f32
  const float* cnn = (const float*)d_in[1];   // [1024,1024,81] f32
  float* out = (float*)d_out;                 // [1024,1024,3] f32
  denoiser_kpn<<<dim3(512), dim3(64), 0, stream>>>(unet, cnn, out);
}